// Round 5
// baseline (126.716 us; speedup 1.0000x reference)
//
#include <hip/hip_runtime.h>

// Problem constants (B=1)
constexpr int C = 32, H = 256, W = 512, K = 10;
constexpr int HW = H * W;               // 131072
constexpr float TEMP = 10000.0f;

// -------- transpose right: CHW f32 -> HWC f32 (pixel-major) ---------------
__global__ __launch_bounds__(256) void conv_right_hwc(
    const float* __restrict__ in, float* __restrict__ out)
{
    __shared__ float t[C][129];          // +1 pad: conflict-free both phases
    const int base = blockIdx.x * 128;
    const int tid = threadIdx.x;
    #pragma unroll
    for (int i = 0; i < 16; ++i) {       // load 32ch x 128px tile, coalesced
        int lin = i * 256 + tid;
        int c = lin >> 7, px = lin & 127;
        t[c][px] = in[c * HW + base + px];
    }
    __syncthreads();
    #pragma unroll
    for (int i = 0; i < 16; ++i) {       // store HWC, fully coalesced
        int lin = i * 256 + tid;
        int px = lin >> 5, c = lin & 31;
        out[(base + px) * C + c] = t[c][px];
    }
}

// -------- main: 8 lanes/pixel = 2 k-phases x 4 channel-quarters ------------
// TLP instead of ILP: 1M threads, 5 k's per thread, <64 VGPRs (no spills).
__global__ __launch_bounds__(256) void disp_kernel_hwc8(
    const float* __restrict__ lchw, const float* __restrict__ rhwc,
    const float* __restrict__ offx, const float* __restrict__ offy,
    float* __restrict__ out)
{
    const int tid = threadIdx.x;
    const int q  = tid & 3;                        // channel quarter
    const int kk = (tid >> 2) & 1;                 // k phase (even/odd)
    const int p  = blockIdx.x * 32 + (tid >> 3);   // pixel id
    const int w = p & (W - 1);
    const int h = p >> 9;

    // left features from CHW; channel set matches dense-sector partition:
    // j 0..3 -> channel 4q+j ; j 4..7 -> channel 16+4q+j
    float lf[8];
    #pragma unroll
    for (int j = 0; j < 4; ++j) lf[j]     = lchw[(4 * q + j) * HW + p];
    #pragma unroll
    for (int j = 0; j < 4; ++j) lf[4 + j] = lchw[(16 + 4 * q + j) * HW + p];

    const float lx = (float)w;
    const float ly = (float)h;   // ref clips y to W-1: no-op (H <= W)
    const float4* rb = (const float4*)rhwc;

    float s[5];

    #pragma unroll
    for (int j = 0; j < 5; ++j) {
        const int k = 2 * j + kk;
        const float ox = offx[k * HW + p];
        const float oy = offy[k * HW + p];

        // reference arithmetic chain, op-for-op (absmax 0.25 proven)
        float rx = fminf(fmaxf(lx - ox, 0.0f), (float)(W - 1));
        float ry = fminf(fmaxf(ly - oy, 0.0f), (float)(H - 1));
        float gx = (rx - (float)(W / 2)) / (float)(W / 2);
        float gy = (ry - (float)(H / 2)) / (float)(H / 2);
        float ix = ((gx + 1.0f) * (float)W - 1.0f) * 0.5f;
        float iy = ((gy + 1.0f) * (float)H - 1.0f) * 0.5f;

        float x0f = floorf(ix), y0f = floorf(iy);
        float wx1 = ix - x0f, wy1 = iy - y0f;
        float wx0 = 1.0f - wx1, wy0 = 1.0f - wy1;
        int x0 = (int)x0f, y0 = (int)y0f;

        // ix in [-0.5,510.5], iy in [-0.5,254.5] => high side always in-bounds
        float ax = (x0 >= 0) ? wx0 : 0.0f;
        float ay = (y0 >= 0) ? wy0 : 0.0f;
        float w00 = ax * ay,   w01 = wx1 * ay;
        float w10 = ax * wy1,  w11 = wx1 * wy1;

        int xi0 = max(x0, 0), yi0 = max(y0, 0);
        int r0 = yi0 * W, r1 = (y0 + 1) * W;
        int b00 = (r0 + xi0) * 8 + q;        // float4 index
        int b01 = (r0 + x0 + 1) * 8 + q;
        int b10 = (r1 + xi0) * 8 + q;
        int b11 = (r1 + x0 + 1) * 8 + q;

        // 4-lane q-group covers each 64-B sector of a record contiguously
        float4 a0 = rb[b00], a1 = rb[b00 + 4];
        float4 b0 = rb[b01], b1 = rb[b01 + 4];
        float4 d0 = rb[b10], d1 = rb[b10 + 4];
        float4 e0 = rb[b11], e1 = rb[b11 + 4];

        float acc = 0.0f;
        acc += fabsf(lf[0] - (w00 * a0.x + w01 * b0.x + w10 * d0.x + w11 * e0.x));
        acc += fabsf(lf[1] - (w00 * a0.y + w01 * b0.y + w10 * d0.y + w11 * e0.y));
        acc += fabsf(lf[2] - (w00 * a0.z + w01 * b0.z + w10 * d0.z + w11 * e0.z));
        acc += fabsf(lf[3] - (w00 * a0.w + w01 * b0.w + w10 * d0.w + w11 * e0.w));
        acc += fabsf(lf[4] - (w00 * a1.x + w01 * b1.x + w10 * d1.x + w11 * e1.x));
        acc += fabsf(lf[5] - (w00 * a1.y + w01 * b1.y + w10 * d1.y + w11 * e1.y));
        acc += fabsf(lf[6] - (w00 * a1.z + w01 * b1.z + w10 * d1.z + w11 * e1.z));
        acc += fabsf(lf[7] - (w00 * a1.w + w01 * b1.w + w10 * d1.w + w11 * e1.w));

        // sum the 4 channel-quarter partials for this (pixel, k)
        acc += __shfl_xor(acc, 1);
        acc += __shfl_xor(acc, 2);
        s[j] = acc * (-TEMP / (float)C);   // -312.5 exact
    }

    // softmax over K: local max over 5, merge across the two k-phases
    float m = s[0];
    #pragma unroll
    for (int j = 1; j < 5; ++j) m = fmaxf(m, s[j]);
    m = fmaxf(m, __shfl_xor(m, 4));

    float den = 0.0f, sx = 0.0f, sy = 0.0f;
    #pragma unroll
    for (int j = 0; j < 5; ++j) {
        const int k = 2 * j + kk;
        float e = __expf(s[j] - m);
        den += e;
        sx += offx[k * HW + p] * e;   // reload offsets: L1/L2-hot broadcast
        sy += offy[k * HW + p] * e;
    }
    den += __shfl_xor(den, 4);
    sx  += __shfl_xor(sx, 4);
    sy  += __shfl_xor(sy, 4);

    float inv = 1.0f / den;
    if ((tid & 7) == 0) {
        out[p]      = sx * inv;
        out[HW + p] = sy * inv;
    }
}

// -------- fallback (round-1 style) if workspace too small -----------------
__global__ __launch_bounds__(256) void disp_kernel_chw(
    const float* __restrict__ left, const float* __restrict__ right,
    const float* __restrict__ offx, const float* __restrict__ offy,
    float* __restrict__ out)
{
    const int p = blockIdx.x * 256 + threadIdx.x;
    const int w = p & (W - 1);
    const int h = p >> 9;
    float lf[C];
    #pragma unroll
    for (int c = 0; c < C; ++c) lf[c] = left[c * HW + p];
    const float lx = (float)w, ly = (float)h;
    float s[K], okx[K], oky[K];
    #pragma unroll
    for (int k = 0; k < K; ++k) {
        const float ox = offx[k * HW + p], oy = offy[k * HW + p];
        okx[k] = ox; oky[k] = oy;
        float rx = fminf(fmaxf(lx - ox, 0.0f), (float)(W - 1));
        float ry = fminf(fmaxf(ly - oy, 0.0f), (float)(H - 1));
        float gx = (rx - 256.0f) / 256.0f, gy = (ry - 128.0f) / 128.0f;
        float ix = ((gx + 1.0f) * (float)W - 1.0f) * 0.5f;
        float iy = ((gy + 1.0f) * (float)H - 1.0f) * 0.5f;
        float x0f = floorf(ix), y0f = floorf(iy);
        float wx1 = ix - x0f, wy1 = iy - y0f;
        float wx0 = 1.0f - wx1, wy0 = 1.0f - wy1;
        int x0 = (int)x0f, y0 = (int)y0f;
        float ax = (x0 >= 0) ? wx0 : 0.0f;
        float ay = (y0 >= 0) ? wy0 : 0.0f;
        float w00 = ax * ay, w01 = wx1 * ay, w10 = ax * wy1, w11 = wx1 * wy1;
        int xi0 = max(x0, 0), yi0 = max(y0, 0);
        int i00 = yi0 * W + xi0, i01 = yi0 * W + x0 + 1;
        int i10 = (y0 + 1) * W + xi0, i11 = (y0 + 1) * W + x0 + 1;
        float acc = 0.0f;
        #pragma unroll
        for (int c = 0; c < C; ++c) {
            const float* rc = right + c * HW;
            acc += fabsf(lf[c] - (w00 * rc[i00] + w01 * rc[i01]
                                + w10 * rc[i10] + w11 * rc[i11]));
        }
        s[k] = acc * (-TEMP / (float)C);
    }
    float m = s[0];
    #pragma unroll
    for (int k = 1; k < K; ++k) m = fmaxf(m, s[k]);
    float den = 0.0f, sx = 0.0f, sy = 0.0f;
    #pragma unroll
    for (int k = 0; k < K; ++k) {
        float e = __expf(s[k] - m);
        den += e; sx += okx[k] * e; sy += oky[k] * e;
    }
    float inv = 1.0f / den;
    out[p] = sx * inv;
    out[HW + p] = sy * inv;
}

extern "C" void kernel_launch(void* const* d_in, const int* in_sizes, int n_in,
                              void* d_out, int out_size, void* d_ws, size_t ws_size,
                              hipStream_t stream) {
    const float* left  = (const float*)d_in[0];
    const float* right = (const float*)d_in[1];
    const float* offx  = (const float*)d_in[2];
    const float* offy  = (const float*)d_in[3];
    float* out = (float*)d_out;

    const size_t need = (size_t)HW * C * sizeof(float);   // 16 MB
    if (ws_size >= need) {
        float* rhwc = (float*)d_ws;
        conv_right_hwc<<<HW / 128, 256, 0, stream>>>(right, rhwc);
        disp_kernel_hwc8<<<HW / 32, 256, 0, stream>>>(left, rhwc, offx, offy, out);
    } else {
        disp_kernel_chw<<<HW / 256, 256, 0, stream>>>(left, right, offx, offy, out);
    }
}

// Round 6
// 121.148 us; speedup vs baseline: 1.0460x; 1.0460x over previous
//
#include <hip/hip_runtime.h>

// Problem constants (B=1)
constexpr int C = 32, H = 256, W = 512, K = 10;
constexpr int HW = H * W;               // 131072
constexpr float TEMP = 10000.0f;
constexpr int NXCD = 8;
constexpr int BAND_PX = HW / NXCD;      // 16384 px = 32 rows per band

// -------- transpose right: CHW f32 -> HWC f32, XCD-band-swizzled ----------
// blockIdx%8 = band, so each XCD produces (and L2-caches) its own band.
__global__ __launch_bounds__(256) void conv_right_hwc(
    const float* __restrict__ in, float* __restrict__ out)
{
    __shared__ float t[C][129];          // +1 pad: conflict-free both phases
    const int band  = blockIdx.x & 7;
    const int inner = blockIdx.x >> 3;   // 0..127
    const int base = band * BAND_PX + inner * 128;
    const int tid = threadIdx.x;
    #pragma unroll
    for (int i = 0; i < 16; ++i) {       // load 32ch x 128px tile, coalesced
        int lin = i * 256 + tid;
        int c = lin >> 7, px = lin & 127;
        t[c][px] = in[c * HW + base + px];
    }
    __syncthreads();
    #pragma unroll
    for (int i = 0; i < 16; ++i) {       // store HWC, fully coalesced
        int lin = i * 256 + tid;
        int px = lin >> 5, c = lin & 31;
        out[(base + px) * C + c] = t[c][px];
    }
}

// -------- main: 8 lanes/pixel = 2 k-phases x 4 channel-quarters -----------
// XCD-band swizzle: blockIdx%8 picks a 32-row band -> per-XCD L2 holds only
// its own ~3.3 MB gather window (band + y-jitter overlap) instead of 16 MB.
__global__ __launch_bounds__(256) void disp_kernel_hwc8(
    const float* __restrict__ lchw, const float* __restrict__ rhwc,
    const float* __restrict__ offx, const float* __restrict__ offy,
    float* __restrict__ out)
{
    const int tid = threadIdx.x;
    const int q  = tid & 3;                        // channel quarter
    const int kk = (tid >> 2) & 1;                 // k phase (even/odd)
    const int band  = blockIdx.x & 7;
    const int inner = blockIdx.x >> 3;             // 0..511
    const int p = band * BAND_PX + inner * 32 + (tid >> 3);
    const int w = p & (W - 1);
    const int h = p >> 9;

    // left features from CHW; channel set matches dense-sector partition:
    // j 0..3 -> channel 4q+j ; j 4..7 -> channel 16+4q+j
    float lf[8];
    #pragma unroll
    for (int j = 0; j < 4; ++j) lf[j]     = lchw[(4 * q + j) * HW + p];
    #pragma unroll
    for (int j = 0; j < 4; ++j) lf[4 + j] = lchw[(16 + 4 * q + j) * HW + p];

    const float lx = (float)w;
    const float ly = (float)h;   // ref clips y to W-1: no-op (H <= W)
    const float4* rb = (const float4*)rhwc;

    float s[5], okx[5], oky[5];

    #pragma unroll
    for (int j = 0; j < 5; ++j) {
        const int k = 2 * j + kk;
        const float ox = offx[k * HW + p];
        const float oy = offy[k * HW + p];
        okx[j] = ox; oky[j] = oy;

        // reference arithmetic chain, op-for-op (absmax 0.25 proven)
        float rx = fminf(fmaxf(lx - ox, 0.0f), (float)(W - 1));
        float ry = fminf(fmaxf(ly - oy, 0.0f), (float)(H - 1));
        float gx = (rx - (float)(W / 2)) / (float)(W / 2);
        float gy = (ry - (float)(H / 2)) / (float)(H / 2);
        float ix = ((gx + 1.0f) * (float)W - 1.0f) * 0.5f;
        float iy = ((gy + 1.0f) * (float)H - 1.0f) * 0.5f;

        float x0f = floorf(ix), y0f = floorf(iy);
        float wx1 = ix - x0f, wy1 = iy - y0f;
        float wx0 = 1.0f - wx1, wy0 = 1.0f - wy1;
        int x0 = (int)x0f, y0 = (int)y0f;

        // ix in [-0.5,510.5], iy in [-0.5,254.5] => high side always in-bounds
        float ax = (x0 >= 0) ? wx0 : 0.0f;
        float ay = (y0 >= 0) ? wy0 : 0.0f;
        float w00 = ax * ay,   w01 = wx1 * ay;
        float w10 = ax * wy1,  w11 = wx1 * wy1;

        int xi0 = max(x0, 0), yi0 = max(y0, 0);
        int r0 = yi0 * W, r1 = (y0 + 1) * W;
        int b00 = (r0 + xi0) * 8 + q;        // float4 index
        int b01 = (r0 + x0 + 1) * 8 + q;
        int b10 = (r1 + xi0) * 8 + q;
        int b11 = (r1 + x0 + 1) * 8 + q;

        // 4-lane q-group covers each 64-B sector of a record contiguously
        float4 a0 = rb[b00], a1 = rb[b00 + 4];
        float4 b0 = rb[b01], b1 = rb[b01 + 4];
        float4 d0 = rb[b10], d1 = rb[b10 + 4];
        float4 e0 = rb[b11], e1 = rb[b11 + 4];

        float acc = 0.0f;
        acc += fabsf(lf[0] - (w00 * a0.x + w01 * b0.x + w10 * d0.x + w11 * e0.x));
        acc += fabsf(lf[1] - (w00 * a0.y + w01 * b0.y + w10 * d0.y + w11 * e0.y));
        acc += fabsf(lf[2] - (w00 * a0.z + w01 * b0.z + w10 * d0.z + w11 * e0.z));
        acc += fabsf(lf[3] - (w00 * a0.w + w01 * b0.w + w10 * d0.w + w11 * e0.w));
        acc += fabsf(lf[4] - (w00 * a1.x + w01 * b1.x + w10 * d1.x + w11 * e1.x));
        acc += fabsf(lf[5] - (w00 * a1.y + w01 * b1.y + w10 * d1.y + w11 * e1.y));
        acc += fabsf(lf[6] - (w00 * a1.z + w01 * b1.z + w10 * d1.z + w11 * e1.z));
        acc += fabsf(lf[7] - (w00 * a1.w + w01 * b1.w + w10 * d1.w + w11 * e1.w));

        // sum the 4 channel-quarter partials for this (pixel, k)
        acc += __shfl_xor(acc, 1);
        acc += __shfl_xor(acc, 2);
        s[j] = acc * (-TEMP / (float)C);   // -312.5 exact
    }

    // softmax over K: local max over 5, merge across the two k-phases
    float m = s[0];
    #pragma unroll
    for (int j = 1; j < 5; ++j) m = fmaxf(m, s[j]);
    m = fmaxf(m, __shfl_xor(m, 4));

    float den = 0.0f, sx = 0.0f, sy = 0.0f;
    #pragma unroll
    for (int j = 0; j < 5; ++j) {
        float e = __expf(s[j] - m);
        den += e;
        sx += okx[j] * e;
        sy += oky[j] * e;
    }
    den += __shfl_xor(den, 4);
    sx  += __shfl_xor(sx, 4);
    sy  += __shfl_xor(sy, 4);

    float inv = 1.0f / den;
    if ((tid & 7) == 0) {
        out[p]      = sx * inv;
        out[HW + p] = sy * inv;
    }
}

// -------- fallback (round-1 style) if workspace too small -----------------
__global__ __launch_bounds__(256) void disp_kernel_chw(
    const float* __restrict__ left, const float* __restrict__ right,
    const float* __restrict__ offx, const float* __restrict__ offy,
    float* __restrict__ out)
{
    const int p = blockIdx.x * 256 + threadIdx.x;
    const int w = p & (W - 1);
    const int h = p >> 9;
    float lf[C];
    #pragma unroll
    for (int c = 0; c < C; ++c) lf[c] = left[c * HW + p];
    const float lx = (float)w, ly = (float)h;
    float s[K], okx[K], oky[K];
    #pragma unroll
    for (int k = 0; k < K; ++k) {
        const float ox = offx[k * HW + p], oy = offy[k * HW + p];
        okx[k] = ox; oky[k] = oy;
        float rx = fminf(fmaxf(lx - ox, 0.0f), (float)(W - 1));
        float ry = fminf(fmaxf(ly - oy, 0.0f), (float)(H - 1));
        float gx = (rx - 256.0f) / 256.0f, gy = (ry - 128.0f) / 128.0f;
        float ix = ((gx + 1.0f) * (float)W - 1.0f) * 0.5f;
        float iy = ((gy + 1.0f) * (float)H - 1.0f) * 0.5f;
        float x0f = floorf(ix), y0f = floorf(iy);
        float wx1 = ix - x0f, wy1 = iy - y0f;
        float wx0 = 1.0f - wx1, wy0 = 1.0f - wy1;
        int x0 = (int)x0f, y0 = (int)y0f;
        float ax = (x0 >= 0) ? wx0 : 0.0f;
        float ay = (y0 >= 0) ? wy0 : 0.0f;
        float w00 = ax * ay, w01 = wx1 * ay, w10 = ax * wy1, w11 = wx1 * wy1;
        int xi0 = max(x0, 0), yi0 = max(y0, 0);
        int i00 = yi0 * W + xi0, i01 = yi0 * W + x0 + 1;
        int i10 = (y0 + 1) * W + xi0, i11 = (y0 + 1) * W + x0 + 1;
        float acc = 0.0f;
        #pragma unroll
        for (int c = 0; c < C; ++c) {
            const float* rc = right + c * HW;
            acc += fabsf(lf[c] - (w00 * rc[i00] + w01 * rc[i01]
                                + w10 * rc[i10] + w11 * rc[i11]));
        }
        s[k] = acc * (-TEMP / (float)C);
    }
    float m = s[0];
    #pragma unroll
    for (int k = 1; k < K; ++k) m = fmaxf(m, s[k]);
    float den = 0.0f, sx = 0.0f, sy = 0.0f;
    #pragma unroll
    for (int k = 0; k < K; ++k) {
        float e = __expf(s[k] - m);
        den += e; sx += okx[k] * e; sy += oky[k] * e;
    }
    float inv = 1.0f / den;
    out[p] = sx * inv;
    out[HW + p] = sy * inv;
}

extern "C" void kernel_launch(void* const* d_in, const int* in_sizes, int n_in,
                              void* d_out, int out_size, void* d_ws, size_t ws_size,
                              hipStream_t stream) {
    const float* left  = (const float*)d_in[0];
    const float* right = (const float*)d_in[1];
    const float* offx  = (const float*)d_in[2];
    const float* offy  = (const float*)d_in[3];
    float* out = (float*)d_out;

    const size_t need = (size_t)HW * C * sizeof(float);   // 16 MB
    if (ws_size >= need) {
        float* rhwc = (float*)d_ws;
        conv_right_hwc<<<HW / 128, 256, 0, stream>>>(right, rhwc);
        disp_kernel_hwc8<<<HW / 32, 256, 0, stream>>>(left, rhwc, offx, offy, out);
    } else {
        disp_kernel_chw<<<HW / 256, 256, 0, stream>>>(left, right, offx, offy, out);
    }
}